// Round 18
// baseline (571.694 us; speedup 1.0000x reference)
//
#include <hip/hip_runtime.h>
#include <hip/hip_bf16.h>

#define NN 50000
#define NE 1600000
#define NB 391          // coarse buckets: dst>>7
#define CBLK 392        // count/scatter blocks; 392*4096 >= NE
#define EPB 4096        // edges per count/scatter block (1024 thr x 4)

typedef __attribute__((ext_vector_type(8))) short bf16x8;
typedef __attribute__((ext_vector_type(4))) float f32x4;

// ---- workspace layout (byte offsets) ----
#define B_HAG   0                              // NN*64 f32
#define B_QW    (B_HAG + NN*64*4)              // 8 f32
#define B_NF    (B_QW + 32)                    // 3*8*64*8 bf16 node-MLP B-frags
#define B_W1B   (B_NF + 3*8*64*8*2)            // 3*8*64*8 bf16 edge B-frags
#define B_XB0   (B_W1B + 3*8*64*8*2)           // NN*16 bf16
#define B_XB1   (B_XB0 + NN*16*2)
#define B_EPK   (B_XB1 + NN*16*2)              // NE uint4
#define B_OFF   (B_EPK + NE*16)                // NN+1 int
#define B_BCNT  (B_OFF + (NN+1)*4)             // CBLK*NB int (local prefix in place)
#define B_BASE  (B_BCNT + CBLK*NB*4)           // NB+1 int
#define B_GTOT  (B_BASE + (NB+1)*4)            // NB int
#define B_END   (B_GTOT + NB*4)

static __device__ __forceinline__ unsigned short f2bf(float f) {
    union { __hip_bfloat16 h; unsigned short u; } cv;
    cv.h = __float2bfloat16(f);
    return cv.u;
}
static __device__ __forceinline__ unsigned pk2(float a, float b) {
    unsigned r;
    asm("v_cvt_pk_bf16_f32 %0, %1, %2" : "=v"(r) : "v"(a), "v"(b));
    return r;
}
static __device__ __forceinline__ float bf2f(unsigned short u) {
    return __uint_as_float((unsigned)u << 16);
}
static __device__ __forceinline__ bf16x8 mk8(unsigned a, unsigned b, unsigned c, unsigned d) {
    union { bf16x8 v; uint4 u; } cv;
    cv.u = make_uint4(a, b, c, d);
    return cv.v;
}

// ---------------------------------------------------------------------------
// fused init: coarse bucket histogram + prep (B-frags, qw) + node init.
// ---------------------------------------------------------------------------
__global__ __launch_bounds__(1024) void fused_init_kernel(
    const float* __restrict__ ew1, const float* __restrict__ eb1,
    const float* __restrict__ nw1, const float* __restrict__ ew2,
    const float* __restrict__ nw2,
    const float* __restrict__ eeW, const float* __restrict__ eeB,
    const float* __restrict__ few, const float* __restrict__ feb,
    unsigned short* __restrict__ w1b, unsigned short* __restrict__ nf,
    float* __restrict__ qw,
    const float* __restrict__ leak, const float* __restrict__ ne_w,
    const float* __restrict__ ne_b,
    unsigned short* __restrict__ xb0, float* __restrict__ hag,
    const int* __restrict__ dst, int* __restrict__ bcnt)
{
    __shared__ int hist[NB];
    int t = threadIdx.x;
    for (int i = t; i < NB; i += 1024) hist[i] = 0;
    __syncthreads();
    int base = blockIdx.x * EPB;
    int b[4];
    #pragma unroll
    for (int i = 0; i < 4; i++) {
        int idx = base + i * 1024 + t;
        b[i] = (idx < NE) ? (dst[idx] >> 7) : -1;
    }
    #pragma unroll
    for (int i = 0; i < 4; i++)
        if (b[i] >= 0) atomicAdd(&hist[b[i]], 1);

    int gtid = blockIdx.x * 1024 + t;
    int gstride = CBLK * 1024;
    for (int idx = gtid; idx < 3 * 8 * 64 * 8; idx += gstride) {
        int l = idx >> 12;
        int r = idx & 4095;
        int f = r >> 9;
        int lane = (r >> 3) & 63;
        int e = r & 7;
        int col = lane & 15;
        int krow = ((lane >> 4) << 3) + e;
        {
            int tt = f >> 1, s = f & 1;
            int k = krow + (s << 5);
            int j = (tt << 4) + col;
            float v = 0.f;
            if (k < 32) {
                v = ew1[l * 3072 + k * 64 + j];
            } else if (k < 36) {
                int f2 = k - 32;
                float acc = 0.f;
                for (int m = 0; m < 16; m++) acc += eeW[f2 * 16 + m] * ew1[l * 3072 + (32 + m) * 64 + j];
                v = acc;
            } else if (k == 36) {
                float acc = eb1[l * 64 + j];
                for (int m = 0; m < 16; m++) acc += eeB[m] * ew1[l * 3072 + (32 + m) * 64 + j];
                v = acc;
            }
            w1b[idx] = f2bf(v);
        }
        {
            float v;
            if (f < 2)      v = ew2[l * 1024 + (f * 32 + krow) * 16 + col];
            else if (f < 6) v = nw1[l * 2048 + krow * 64 + (f - 2) * 16 + col];
            else            v = nw2[l * 1024 + ((f - 6) * 32 + krow) * 16 + col];
            nf[idx] = f2bf(v);
        }
    }
    if (gtid < 4) {
        float s = 0.f;
        for (int k = 0; k < 16; k++) s += eeW[gtid * 16 + k] * few[k];
        qw[gtid] = s;
    } else if (gtid == 4) {
        float s = feb[0];
        for (int k = 0; k < 16; k++) s += eeB[k] * few[k];
        qw[4] = s;
    }
    if (gtid < NN) {
        int n = gtid;
        float la = leak[n];
        float v[16];
        #pragma unroll
        for (int i = 0; i < 16; i++) v[i] = la * ne_w[i] + ne_b[i];
        unsigned pk[8];
        #pragma unroll
        for (int i = 0; i < 8; i++) pk[i] = pk2(v[2 * i], v[2 * i + 1]);
        uint4* xo = reinterpret_cast<uint4*>(xb0 + (size_t)n * 16);
        xo[0] = make_uint4(pk[0], pk[1], pk[2], pk[3]);
        xo[1] = make_uint4(pk[4], pk[5], pk[6], pk[7]);
        float4 z = {0.f, 0.f, 0.f, 0.f};
        float4* hp = reinterpret_cast<float4*>(hag + (size_t)n * 64);
        #pragma unroll
        for (int j = 0; j < 16; j++) hp[j] = z;
    }

    __syncthreads();
    for (int i = t; i < NB; i += 1024) bcnt[blockIdx.x * NB + i] = hist[i];
}

// ---------------------------------------------------------------------------
// B1: per-bucket scan across the CBLK block counts (one block per bucket).
// ---------------------------------------------------------------------------
__global__ __launch_bounds__(512) void scan_blocks_kernel(
    int* __restrict__ bcnt, int* __restrict__ gtot)
{
    __shared__ int sm[512];
    int b = blockIdx.x;      // bucket
    int t = threadIdx.x;
    int v = (t < CBLK) ? bcnt[t * NB + b] : 0;
    sm[t] = v;
    __syncthreads();
    for (int o = 1; o < 512; o <<= 1) {
        int x = (t >= o) ? sm[t - o] : 0;
        __syncthreads();
        sm[t] += x;
        __syncthreads();
    }
    if (t < CBLK) bcnt[t * NB + b] = sm[t] - v;   // exclusive prefix within bucket
    if (t == 511) gtot[b] = sm[511];
}

// ---------------------------------------------------------------------------
// B2: scan bucket totals -> gbase[NB+1]
// ---------------------------------------------------------------------------
__global__ __launch_bounds__(512) void scan_top_kernel(
    const int* __restrict__ gtot, int* __restrict__ gbase)
{
    __shared__ int sm[512];
    int t = threadIdx.x;
    int v = (t < NB) ? gtot[t] : 0;
    sm[t] = v;
    __syncthreads();
    for (int o = 1; o < 512; o <<= 1) {
        int x = (t >= o) ? sm[t - o] : 0;
        __syncthreads();
        sm[t] += x;
        __syncthreads();
    }
    if (t < NB) gbase[t] = sm[t] - v;
    if (t == 0) gbase[NB] = NE;
}

// ---------------------------------------------------------------------------
// C: coarse scatter + q, software-pipelined.
// ---------------------------------------------------------------------------
__global__ __launch_bounds__(1024) void bucket_scatter_kernel(
    const int* __restrict__ ei, const float* __restrict__ pa,
    const int* __restrict__ bcnt, const int* __restrict__ gbase,
    const float* __restrict__ qw,
    float* __restrict__ qout, uint4* __restrict__ epk)
{
    __shared__ int hist[NB];
    int t = threadIdx.x;
    for (int i = t; i < NB; i += 1024) hist[i] = 0;
    __syncthreads();
    int base = blockIdx.x * EPB;
    float q0 = qw[0], q1 = qw[1], q2 = qw[2], q3 = qw[3], q4 = qw[4];
    int d[4], s[4];
    float4 p[4];
    #pragma unroll
    for (int i = 0; i < 4; i++) {
        int idx = base + i * 1024 + t;
        if (idx < NE) {
            d[i] = ei[NE + idx];
            s[i] = ei[idx];
            p[i] = reinterpret_cast<const float4*>(pa)[idx];
        } else {
            d[i] = -1;
        }
    }
    #pragma unroll
    for (int i = 0; i < 4; i++) {
        int idx = base + i * 1024 + t;
        if (d[i] >= 0)
            qout[idx] = q4 + p[i].x * q0 + p[i].y * q1 + p[i].z * q2 + p[i].w * q3;
    }
    int lr[4];
    #pragma unroll
    for (int i = 0; i < 4; i++)
        if (d[i] >= 0) lr[i] = atomicAdd(&hist[d[i] >> 7], 1);
    int bs[4];
    #pragma unroll
    for (int i = 0; i < 4; i++)
        if (d[i] >= 0) {
            int b = d[i] >> 7;
            bs[i] = gbase[b] + bcnt[blockIdx.x * NB + b];
        }
    #pragma unroll
    for (int i = 0; i < 4; i++)
        if (d[i] >= 0) {
            uint4 v;
            v.x = (unsigned)s[i];
            v.y = (unsigned)d[i];
            v.z = pk2(p[i].x, p[i].y);
            v.w = pk2(p[i].z, p[i].w);
            epk[bs[i] + lr[i]] = v;
        }
}

// ---------------------------------------------------------------------------
// D: fine sort within each coarse bucket + emit off[] (loads batched)
// ---------------------------------------------------------------------------
__global__ __launch_bounds__(1024) void fine_sort_kernel(
    const int* __restrict__ gbase, uint4* __restrict__ epk, int* __restrict__ off)
{
    __shared__ int hist[128];
    __shared__ int fb[128];
    int t = threadIdx.x;
    int b = blockIdx.x;
    int S = gbase[b], E = gbase[b + 1];
    if (t < 128) hist[t] = 0;
    __syncthreads();

    uint4 r[12];
    #pragma unroll
    for (int i = 0; i < 12; i++) {
        int gi = S + i * 1024 + t;
        if (gi < E) r[i] = epk[gi];
    }
    int lr[12];
    #pragma unroll
    for (int i = 0; i < 12; i++) {
        int gi = S + i * 1024 + t;
        if (gi < E) lr[i] = atomicAdd(&hist[(int)(r[i].y & 127u)], 1);
    }
    __syncthreads();
    if (t < 128) fb[t] = hist[t];
    __syncthreads();
    for (int o = 1; o < 128; o <<= 1) {
        int v = 0;
        if (t < 128 && t >= o) v = fb[t - o];
        __syncthreads();
        if (t < 128) fb[t] += v;
        __syncthreads();
    }
    int d0 = b << 7;
    if (t < 128 && d0 + t < NN) off[d0 + t] = S + fb[t] - hist[t];
    if (b == NB - 1 && t == 0) off[NN] = NE;
    __syncthreads();
    #pragma unroll
    for (int i = 0; i < 12; i++) {
        int gi = S + i * 1024 + t;
        if (gi < E) {
            int fd = (int)(r[i].y & 127u);
            int pos = S + (fb[fd] - hist[fd]) + lr[i];
            epk[pos] = r[i];
        }
    }
}

// ---------------------------------------------------------------------------
// MFMA edge kernel, half-window staging: hbuf holds only 32 edges at a time
// ([64 j][36 edge-stride] bf16 = 4.6KB/wave), processed in two stage+epilogue
// passes. Same math/order as the R13 structure; the d cursor carries across
// halves (boundary segments get one extra coalesced atomic). LDS/block 9.2KB
// -> 16 blocks/CU -> ~4x the resident waves for latency hiding.
// ---------------------------------------------------------------------------
__global__ __launch_bounds__(128, 8) void edge_mfma_kernel(
    const unsigned short* __restrict__ xb,
    const uint4* __restrict__ epk,
    const int* __restrict__ off,
    const unsigned short* __restrict__ w1b,
    float* __restrict__ hag)
{
    __shared__ unsigned short hbuf[2][64 * 36];
    int tid = threadIdx.x;
    int lane = tid & 63;
    int wid = tid >> 6;
    int wave = blockIdx.x * 2 + wid;
    int base = wave * 64;
    if (base >= NE) return;
    int ar = lane & 15;
    int ap = lane >> 4;
    unsigned short* hb = &hbuf[wid][0];

    uint4 ev0 = epk[base + 0  + ar];
    uint4 ev1 = epk[base + 16 + ar];
    uint4 ev2 = epk[base + 32 + ar];
    uint4 ev3 = epk[base + 48 + ar];

    int r0 = (ap < 2) ? (int)ev0.y : (int)ev0.x;
    int r1 = (ap < 2) ? (int)ev1.y : (int)ev1.x;
    int r2 = (ap < 2) ? (int)ev2.y : (int)ev2.x;
    int r3 = (ap < 2) ? (int)ev3.y : (int)ev3.x;
    int half = (ap & 1) * 8;
    bf16x8 a00 = *reinterpret_cast<const bf16x8*>(xb + (size_t)r0 * 16 + half);
    bf16x8 a01 = *reinterpret_cast<const bf16x8*>(xb + (size_t)r1 * 16 + half);
    bf16x8 a02 = *reinterpret_cast<const bf16x8*>(xb + (size_t)r2 * 16 + half);
    bf16x8 a03 = *reinterpret_cast<const bf16x8*>(xb + (size_t)r3 * 16 + half);

    int d0 = __builtin_amdgcn_readfirstlane((int)ev0.y);

    bf16x8 Bf[8];
    const bf16x8* w1v = reinterpret_cast<const bf16x8*>(w1b);
    #pragma unroll
    for (int i = 0; i < 8; i++) Bf[i] = w1v[i * 64 + lane];

#define DO_TILE(EV, A0, HT) do {                                               \
    bf16x8 a1 = (bf16x8)0;                                                     \
    if (ap == 0) {                                                             \
        a1[0] = (short)(EV.z & 0xffffu);                                       \
        a1[1] = (short)(EV.z >> 16);                                           \
        a1[2] = (short)(EV.w & 0xffffu);                                       \
        a1[3] = (short)(EV.w >> 16);                                           \
        a1[4] = (short)0x3f80;                                                 \
    }                                                                          \
    f32x4 C0 = {0.f, 0.f, 0.f, 0.f}, C1 = C0, C2 = C0, C3 = C0;                \
    C0 = __builtin_amdgcn_mfma_f32_16x16x32_bf16(A0, Bf[0], C0, 0, 0, 0);      \
    C0 = __builtin_amdgcn_mfma_f32_16x16x32_bf16(a1, Bf[1], C0, 0, 0, 0);      \
    C1 = __builtin_amdgcn_mfma_f32_16x16x32_bf16(A0, Bf[2], C1, 0, 0, 0);      \
    C1 = __builtin_amdgcn_mfma_f32_16x16x32_bf16(a1, Bf[3], C1, 0, 0, 0);      \
    C2 = __builtin_amdgcn_mfma_f32_16x16x32_bf16(A0, Bf[4], C2, 0, 0, 0);      \
    C2 = __builtin_amdgcn_mfma_f32_16x16x32_bf16(a1, Bf[5], C2, 0, 0, 0);      \
    C3 = __builtin_amdgcn_mfma_f32_16x16x32_bf16(A0, Bf[6], C3, 0, 0, 0);      \
    C3 = __builtin_amdgcn_mfma_f32_16x16x32_bf16(a1, Bf[7], C3, 0, 0, 0);      \
    int eoff = (HT) * 16 + ap * 4;                                             \
    {                                                                          \
        unsigned lov = pk2(fmaxf(C0[0], 0.f), fmaxf(C0[1], 0.f));              \
        unsigned hiv = pk2(fmaxf(C0[2], 0.f), fmaxf(C0[3], 0.f));              \
        *reinterpret_cast<uint2*>(hb + (0 * 16 + ar) * 36 + eoff) = make_uint2(lov, hiv); \
    }                                                                          \
    {                                                                          \
        unsigned lov = pk2(fmaxf(C1[0], 0.f), fmaxf(C1[1], 0.f));              \
        unsigned hiv = pk2(fmaxf(C1[2], 0.f), fmaxf(C1[3], 0.f));              \
        *reinterpret_cast<uint2*>(hb + (1 * 16 + ar) * 36 + eoff) = make_uint2(lov, hiv); \
    }                                                                          \
    {                                                                          \
        unsigned lov = pk2(fmaxf(C2[0], 0.f), fmaxf(C2[1], 0.f));              \
        unsigned hiv = pk2(fmaxf(C2[2], 0.f), fmaxf(C2[3], 0.f));              \
        *reinterpret_cast<uint2*>(hb + (2 * 16 + ar) * 36 + eoff) = make_uint2(lov, hiv); \
    }                                                                          \
    {                                                                          \
        unsigned lov = pk2(fmaxf(C3[0], 0.f), fmaxf(C3[1], 0.f));              \
        unsigned hiv = pk2(fmaxf(C3[2], 0.f), fmaxf(C3[3], 0.f));              \
        *reinterpret_cast<uint2*>(hb + (3 * 16 + ar) * 36 + eoff) = make_uint2(lov, hiv); \
    }                                                                          \
} while (0)

#define EPILOGUE(HSTART, HLIM) do {                                            \
    const unsigned short* hr = hb + lane * 36;                                 \
    while (e < (HLIM)) {                                                       \
        int segend = off[d + 1];                                               \
        int eend = segend < (HLIM) ? segend : (HLIM);                          \
        float acc = 0.f;                                                       \
        int i = e - (HSTART), iend = eend - (HSTART);                          \
        for (; (i & 3) != 0 && i < iend; ++i) acc += bf2f(hr[i]);              \
        for (; i + 4 <= iend; i += 4) {                                        \
            uint2 u = *reinterpret_cast<const uint2*>(hr + i);                 \
            acc += __uint_as_float(u.x << 16) + __uint_as_float(u.x & 0xffff0000u) \
                 + __uint_as_float(u.y << 16) + __uint_as_float(u.y & 0xffff0000u); \
        }                                                                      \
        for (; i < iend; ++i) acc += bf2f(hr[i]);                              \
        unsafeAtomicAdd(&hag[(size_t)d * 64 + lane], acc);                     \
        e = eend;                                                              \
        if (segend <= (HLIM)) ++d;                                             \
    }                                                                          \
} while (0)

    // half 0: tiles 0,1 -> epilogue over [base, base+32)
    DO_TILE(ev0, a00, 0);
    DO_TILE(ev1, a01, 1);
    asm volatile("s_waitcnt lgkmcnt(0)" ::: "memory");
    __builtin_amdgcn_sched_barrier(0);
    int d = d0;
    int e = base;
    EPILOGUE(base, base + 32);
    asm volatile("s_waitcnt lgkmcnt(0)" ::: "memory");
    __builtin_amdgcn_sched_barrier(0);

    // half 1: tiles 2,3 -> epilogue over [base+32, base+64)
    DO_TILE(ev2, a02, 0);
    DO_TILE(ev3, a03, 1);
    asm volatile("s_waitcnt lgkmcnt(0)" ::: "memory");
    __builtin_amdgcn_sched_barrier(0);
    EPILOGUE(base + 32, base + 64);
#undef DO_TILE
#undef EPILOGUE
}

// ---------------------------------------------------------------------------
// node update via MFMA (unchanged): per wave = 16 nodes.
// ---------------------------------------------------------------------------
__global__ __launch_bounds__(256) void node_mfma_kernel(
    const unsigned short* __restrict__ xb, unsigned short* __restrict__ xbn,
    float* __restrict__ hag, const int* __restrict__ off,
    const unsigned short* __restrict__ nf,
    const float* __restrict__ eb2,
    const float* __restrict__ nb1, const float* __restrict__ nb2,
    const float* __restrict__ fnw, const float* __restrict__ fnb,
    float* __restrict__ Hout, int writeH)
{
    __shared__ unsigned short aggt[4][16 * 16];
    __shared__ unsigned short ht[4][16 * 64];
    __shared__ float ot[4][16 * 16];
    int tid = threadIdx.x;
    int lane = tid & 63;
    int wid = tid >> 6;
    int wave = blockIdx.x * 4 + wid;
    int n0 = wave * 16;
    if (n0 >= NN) return;
    int nr = lane & 15;
    int ap = lane >> 4;

    bf16x8 Bf[8];
    const bf16x8* nfv = reinterpret_cast<const bf16x8*>(nf);
    #pragma unroll
    for (int i = 0; i < 8; i++) Bf[i] = nfv[i * 64 + lane];

    float* hrow = hag + (size_t)(n0 + nr) * 64 + ap * 8;
    float4* h0p = reinterpret_cast<float4*>(hrow);
    float4* h1p = reinterpret_cast<float4*>(hrow + 32);
    float4 ha = h0p[0], hc = h0p[1];
    float4 he = h1p[0], hg = h1p[1];
    float4 z = {0.f, 0.f, 0.f, 0.f};
    h0p[0] = z; h0p[1] = z; h1p[0] = z; h1p[1] = z;
    bf16x8 agA0 = mk8(pk2(ha.x, ha.y), pk2(ha.z, ha.w), pk2(hc.x, hc.y), pk2(hc.z, hc.w));
    bf16x8 agA1 = mk8(pk2(he.x, he.y), pk2(he.z, he.w), pk2(hg.x, hg.y), pk2(hg.z, hg.w));
    f32x4 Cag = {0.f, 0.f, 0.f, 0.f};
    Cag = __builtin_amdgcn_mfma_f32_16x16x32_bf16(agA0, Bf[0], Cag, 0, 0, 0);
    Cag = __builtin_amdgcn_mfma_f32_16x16x32_bf16(agA1, Bf[1], Cag, 0, 0, 0);

    int bn = n0 + ap * 4;
    int o0 = off[bn], o1 = off[bn + 1], o2 = off[bn + 2], o3 = off[bn + 3], o4 = off[bn + 4];
    float ebv = eb2[nr];
    {
        int dgs[4] = {o1 - o0, o2 - o1, o3 - o2, o4 - o3};
        #pragma unroll
        for (int r = 0; r < 4; r++) {
            float inv = 1.0f / (float)(dgs[r] > 0 ? dgs[r] : 1);
            float val = Cag[r] * inv + ((dgs[r] > 0) ? ebv : 0.f);
            aggt[wid][(ap * 4 + r) * 16 + nr] = f2bf(val);
        }
    }
    asm volatile("s_waitcnt lgkmcnt(0)" ::: "memory");
    __builtin_amdgcn_sched_barrier(0);

    bf16x8 uA;
    if (ap < 2) uA = *reinterpret_cast<const bf16x8*>(xb + (size_t)(n0 + nr) * 16 + ap * 8);
    else        uA = *reinterpret_cast<const bf16x8*>(&aggt[wid][nr * 16 + (ap - 2) * 8]);

    f32x4 Ch0 = {0.f, 0.f, 0.f, 0.f}, Ch1 = Ch0, Ch2 = Ch0, Ch3 = Ch0;
    Ch0 = __builtin_amdgcn_mfma_f32_16x16x32_bf16(uA, Bf[2], Ch0, 0, 0, 0);
    Ch1 = __builtin_amdgcn_mfma_f32_16x16x32_bf16(uA, Bf[3], Ch1, 0, 0, 0);
    Ch2 = __builtin_amdgcn_mfma_f32_16x16x32_bf16(uA, Bf[4], Ch2, 0, 0, 0);
    Ch3 = __builtin_amdgcn_mfma_f32_16x16x32_bf16(uA, Bf[5], Ch3, 0, 0, 0);

#define H_EPI(C, TT) do {                                                      \
    int j = (TT) * 16 + nr;                                                    \
    float bv = nb1[j];                                                         \
    _Pragma("unroll")                                                          \
    for (int r = 0; r < 4; r++) {                                              \
        float h = fmaxf(C[r] + bv, 0.f);                                       \
        ht[wid][(ap * 4 + r) * 64 + j] = f2bf(h);                              \
    }                                                                          \
} while (0)
    H_EPI(Ch0, 0); H_EPI(Ch1, 1); H_EPI(Ch2, 2); H_EPI(Ch3, 3);
#undef H_EPI

    asm volatile("s_waitcnt lgkmcnt(0)" ::: "memory");
    __builtin_amdgcn_sched_barrier(0);

    bf16x8 hA0 = *reinterpret_cast<const bf16x8*>(&ht[wid][nr * 64 + ap * 8]);
    bf16x8 hA1 = *reinterpret_cast<const bf16x8*>(&ht[wid][nr * 64 + 32 + ap * 8]);
    f32x4 Co = {0.f, 0.f, 0.f, 0.f};
    Co = __builtin_amdgcn_mfma_f32_16x16x32_bf16(hA0, Bf[6], Co, 0, 0, 0);
    Co = __builtin_amdgcn_mfma_f32_16x16x32_bf16(hA1, Bf[7], Co, 0, 0, 0);
    {
        float bv = nb2[nr];
        #pragma unroll
        for (int r = 0; r < 4; r++) ot[wid][(ap * 4 + r) * 16 + nr] = Co[r] + bv;
    }
    asm volatile("s_waitcnt lgkmcnt(0)" ::: "memory");
    __builtin_amdgcn_sched_barrier(0);

    if (lane < 16) {
        const float* orow = &ot[wid][lane * 16];
        float o[16];
        #pragma unroll
        for (int k = 0; k < 16; k++) o[k] = orow[k];
        unsigned pk[8];
        #pragma unroll
        for (int i = 0; i < 8; i++) pk[i] = pk2(o[2 * i], o[2 * i + 1]);
        uint4* xo = reinterpret_cast<uint4*>(xbn + (size_t)(n0 + lane) * 16);
        xo[0] = make_uint4(pk[0], pk[1], pk[2], pk[3]);
        xo[1] = make_uint4(pk[4], pk[5], pk[6], pk[7]);
        if (writeH) {
            float s = fnb[0];
            #pragma unroll
            for (int k = 0; k < 16; k++) s += o[k] * fnw[k];
            Hout[n0 + lane] = s;
        }
    }
}

extern "C" void kernel_launch(void* const* d_in, const int* in_sizes, int n_in,
                              void* d_out, int out_size, void* d_ws, size_t ws_size,
                              hipStream_t stream)
{
    const float* leak = (const float*)d_in[0];
    const float* pa   = (const float*)d_in[1];
    const int*   ei   = (const int*)d_in[2];
    const float* neww = (const float*)d_in[3];
    const float* newb = (const float*)d_in[4];
    const float* eeW  = (const float*)d_in[5];
    const float* eeB  = (const float*)d_in[6];
    const float* ew1  = (const float*)d_in[7];
    const float* eb1  = (const float*)d_in[8];
    const float* ew2  = (const float*)d_in[9];
    const float* eb2  = (const float*)d_in[10];
    const float* nw1  = (const float*)d_in[11];
    const float* nb1  = (const float*)d_in[12];
    const float* nw2  = (const float*)d_in[13];
    const float* nb2  = (const float*)d_in[14];
    const float* fnw  = (const float*)d_in[15];
    const float* fnb  = (const float*)d_in[16];
    const float* few  = (const float*)d_in[17];
    const float* feb  = (const float*)d_in[18];

    char* wsb = (char*)d_ws;
    float*          hag   = (float*)(wsb + B_HAG);
    float*          qw    = (float*)(wsb + B_QW);
    unsigned short* nf    = (unsigned short*)(wsb + B_NF);
    unsigned short* w1b   = (unsigned short*)(wsb + B_W1B);
    unsigned short* xb0   = (unsigned short*)(wsb + B_XB0);
    unsigned short* xb1   = (unsigned short*)(wsb + B_XB1);
    uint4*          epk   = (uint4*)(wsb + B_EPK);
    int*            off   = (int*)(wsb + B_OFF);
    int*            bcnt  = (int*)(wsb + B_BCNT);
    int*            gbase = (int*)(wsb + B_BASE);
    int*            gtot  = (int*)(wsb + B_GTOT);

    float* H = (float*)d_out;
    float* q = (float*)d_out + NN;
    const int* dstp = ei + NE;

    fused_init_kernel<<<CBLK, 1024, 0, stream>>>(
        ew1, eb1, nw1, ew2, nw2, eeW, eeB, few, feb, w1b, nf, qw,
        leak, neww, newb, xb0, hag, dstp, bcnt);
    scan_blocks_kernel<<<NB, 512, 0, stream>>>(bcnt, gtot);
    scan_top_kernel<<<1, 512, 0, stream>>>(gtot, gbase);
    bucket_scatter_kernel<<<CBLK, 1024, 0, stream>>>(ei, pa, bcnt, gbase, qw, q, epk);
    fine_sort_kernel<<<NB, 1024, 0, stream>>>(gbase, epk, off);

    int nwaves = NN / 16;                       // 3125
    int nblocks = (nwaves + 3) / 4;             // 782

    unsigned short* xcur = xb0;
    unsigned short* xnxt = xb1;
    for (int l = 0; l < 3; l++) {
        edge_mfma_kernel<<<NE / 128, 128, 0, stream>>>(
            xcur, epk, off, w1b + l * 4096, hag);
        node_mfma_kernel<<<nblocks, 256, 0, stream>>>(
            xcur, xnxt, hag, off, nf + l * 4096, eb2 + l * 16,
            nb1 + l * 64, nb2 + l * 16, fnw, fnb, H, (l == 2) ? 1 : 0);
        unsigned short* tmp = xcur; xcur = xnxt; xnxt = tmp;
    }
}

// Round 19
// 198.623 us; speedup vs baseline: 2.8783x; 2.8783x over previous
//
#include <hip/hip_runtime.h>
#include <hip/hip_bf16.h>

#define NN 50000
#define NE 1600000
#define NB 391          // coarse buckets: dst>>7
#define CBLK 392        // count/scatter blocks; 392*4096 >= NE
#define EPB 4096        // edges per count/scatter block (1024 thr x 4)

typedef __attribute__((ext_vector_type(8))) short bf16x8;
typedef __attribute__((ext_vector_type(4))) float f32x4;

// ---- workspace layout (byte offsets) ----
#define B_HAG   0                              // NN*64 f32
#define B_QW    (B_HAG + NN*64*4)              // 8 f32
#define B_NF    (B_QW + 32)                    // 3*8*64*8 bf16 node-MLP B-frags
#define B_W1B   (B_NF + 3*8*64*8*2)            // 3*8*64*8 bf16 edge B-frags
#define B_XB0   (B_W1B + 3*8*64*8*2)           // NN*16 bf16
#define B_XB1   (B_XB0 + NN*16*2)
#define B_EPK   (B_XB1 + NN*16*2)              // NE uint4
#define B_OFF   (B_EPK + NE*16)                // NN+1 int
#define B_BCNT  (B_OFF + (NN+1)*4)             // CBLK*NB int (local prefix in place)
#define B_BASE  (B_BCNT + CBLK*NB*4)           // NB+1 int
#define B_GTOT  (B_BASE + (NB+1)*4)            // NB int
#define B_END   (B_GTOT + NB*4)

static __device__ __forceinline__ unsigned short f2bf(float f) {
    union { __hip_bfloat16 h; unsigned short u; } cv;
    cv.h = __float2bfloat16(f);
    return cv.u;
}
static __device__ __forceinline__ unsigned pk2(float a, float b) {
    unsigned r;
    asm("v_cvt_pk_bf16_f32 %0, %1, %2" : "=v"(r) : "v"(a), "v"(b));
    return r;
}
static __device__ __forceinline__ float bf2f(unsigned short u) {
    return __uint_as_float((unsigned)u << 16);
}
static __device__ __forceinline__ bf16x8 mk8(unsigned a, unsigned b, unsigned c, unsigned d) {
    union { bf16x8 v; uint4 u; } cv;
    cv.u = make_uint4(a, b, c, d);
    return cv.v;
}

// ---------------------------------------------------------------------------
// fused init: coarse bucket histogram + prep (B-frags, qw) + node init.
// ---------------------------------------------------------------------------
__global__ __launch_bounds__(1024) void fused_init_kernel(
    const float* __restrict__ ew1, const float* __restrict__ eb1,
    const float* __restrict__ nw1, const float* __restrict__ ew2,
    const float* __restrict__ nw2,
    const float* __restrict__ eeW, const float* __restrict__ eeB,
    const float* __restrict__ few, const float* __restrict__ feb,
    unsigned short* __restrict__ w1b, unsigned short* __restrict__ nf,
    float* __restrict__ qw,
    const float* __restrict__ leak, const float* __restrict__ ne_w,
    const float* __restrict__ ne_b,
    unsigned short* __restrict__ xb0, float* __restrict__ hag,
    const int* __restrict__ dst, int* __restrict__ bcnt)
{
    __shared__ int hist[NB];
    int t = threadIdx.x;
    for (int i = t; i < NB; i += 1024) hist[i] = 0;
    __syncthreads();
    int base = blockIdx.x * EPB;
    int b[4];
    #pragma unroll
    for (int i = 0; i < 4; i++) {
        int idx = base + i * 1024 + t;
        b[i] = (idx < NE) ? (dst[idx] >> 7) : -1;
    }
    #pragma unroll
    for (int i = 0; i < 4; i++)
        if (b[i] >= 0) atomicAdd(&hist[b[i]], 1);

    int gtid = blockIdx.x * 1024 + t;
    int gstride = CBLK * 1024;
    for (int idx = gtid; idx < 3 * 8 * 64 * 8; idx += gstride) {
        int l = idx >> 12;
        int r = idx & 4095;
        int f = r >> 9;
        int lane = (r >> 3) & 63;
        int e = r & 7;
        int col = lane & 15;
        int krow = ((lane >> 4) << 3) + e;
        {
            int tt = f >> 1, s = f & 1;
            int k = krow + (s << 5);
            int j = (tt << 4) + col;
            float v = 0.f;
            if (k < 32) {
                v = ew1[l * 3072 + k * 64 + j];
            } else if (k < 36) {
                int f2 = k - 32;
                float acc = 0.f;
                for (int m = 0; m < 16; m++) acc += eeW[f2 * 16 + m] * ew1[l * 3072 + (32 + m) * 64 + j];
                v = acc;
            } else if (k == 36) {
                float acc = eb1[l * 64 + j];
                for (int m = 0; m < 16; m++) acc += eeB[m] * ew1[l * 3072 + (32 + m) * 64 + j];
                v = acc;
            }
            w1b[idx] = f2bf(v);
        }
        {
            float v;
            if (f < 2)      v = ew2[l * 1024 + (f * 32 + krow) * 16 + col];
            else if (f < 6) v = nw1[l * 2048 + krow * 64 + (f - 2) * 16 + col];
            else            v = nw2[l * 1024 + ((f - 6) * 32 + krow) * 16 + col];
            nf[idx] = f2bf(v);
        }
    }
    if (gtid < 4) {
        float s = 0.f;
        for (int k = 0; k < 16; k++) s += eeW[gtid * 16 + k] * few[k];
        qw[gtid] = s;
    } else if (gtid == 4) {
        float s = feb[0];
        for (int k = 0; k < 16; k++) s += eeB[k] * few[k];
        qw[4] = s;
    }
    if (gtid < NN) {
        int n = gtid;
        float la = leak[n];
        float v[16];
        #pragma unroll
        for (int i = 0; i < 16; i++) v[i] = la * ne_w[i] + ne_b[i];
        unsigned pk[8];
        #pragma unroll
        for (int i = 0; i < 8; i++) pk[i] = pk2(v[2 * i], v[2 * i + 1]);
        uint4* xo = reinterpret_cast<uint4*>(xb0 + (size_t)n * 16);
        xo[0] = make_uint4(pk[0], pk[1], pk[2], pk[3]);
        xo[1] = make_uint4(pk[4], pk[5], pk[6], pk[7]);
        float4 z = {0.f, 0.f, 0.f, 0.f};
        float4* hp = reinterpret_cast<float4*>(hag + (size_t)n * 64);
        #pragma unroll
        for (int j = 0; j < 16; j++) hp[j] = z;
    }

    __syncthreads();
    for (int i = t; i < NB; i += 1024) bcnt[blockIdx.x * NB + i] = hist[i];
}

// ---------------------------------------------------------------------------
// B1: per-bucket scan across the CBLK block counts (one block per bucket).
// ---------------------------------------------------------------------------
__global__ __launch_bounds__(512) void scan_blocks_kernel(
    int* __restrict__ bcnt, int* __restrict__ gtot)
{
    __shared__ int sm[512];
    int b = blockIdx.x;      // bucket
    int t = threadIdx.x;
    int v = (t < CBLK) ? bcnt[t * NB + b] : 0;
    sm[t] = v;
    __syncthreads();
    for (int o = 1; o < 512; o <<= 1) {
        int x = (t >= o) ? sm[t - o] : 0;
        __syncthreads();
        sm[t] += x;
        __syncthreads();
    }
    if (t < CBLK) bcnt[t * NB + b] = sm[t] - v;   // exclusive prefix within bucket
    if (t == 511) gtot[b] = sm[511];
}

// ---------------------------------------------------------------------------
// B2: scan bucket totals -> gbase[NB+1]
// ---------------------------------------------------------------------------
__global__ __launch_bounds__(512) void scan_top_kernel(
    const int* __restrict__ gtot, int* __restrict__ gbase)
{
    __shared__ int sm[512];
    int t = threadIdx.x;
    int v = (t < NB) ? gtot[t] : 0;
    sm[t] = v;
    __syncthreads();
    for (int o = 1; o < 512; o <<= 1) {
        int x = (t >= o) ? sm[t - o] : 0;
        __syncthreads();
        sm[t] += x;
        __syncthreads();
    }
    if (t < NB) gbase[t] = sm[t] - v;
    if (t == 0) gbase[NB] = NE;
}

// ---------------------------------------------------------------------------
// C: coarse scatter + q, software-pipelined.
// ---------------------------------------------------------------------------
__global__ __launch_bounds__(1024) void bucket_scatter_kernel(
    const int* __restrict__ ei, const float* __restrict__ pa,
    const int* __restrict__ bcnt, const int* __restrict__ gbase,
    const float* __restrict__ qw,
    float* __restrict__ qout, uint4* __restrict__ epk)
{
    __shared__ int hist[NB];
    int t = threadIdx.x;
    for (int i = t; i < NB; i += 1024) hist[i] = 0;
    __syncthreads();
    int base = blockIdx.x * EPB;
    float q0 = qw[0], q1 = qw[1], q2 = qw[2], q3 = qw[3], q4 = qw[4];
    int d[4], s[4];
    float4 p[4];
    #pragma unroll
    for (int i = 0; i < 4; i++) {
        int idx = base + i * 1024 + t;
        if (idx < NE) {
            d[i] = ei[NE + idx];
            s[i] = ei[idx];
            p[i] = reinterpret_cast<const float4*>(pa)[idx];
        } else {
            d[i] = -1;
        }
    }
    #pragma unroll
    for (int i = 0; i < 4; i++) {
        int idx = base + i * 1024 + t;
        if (d[i] >= 0)
            qout[idx] = q4 + p[i].x * q0 + p[i].y * q1 + p[i].z * q2 + p[i].w * q3;
    }
    int lr[4];
    #pragma unroll
    for (int i = 0; i < 4; i++)
        if (d[i] >= 0) lr[i] = atomicAdd(&hist[d[i] >> 7], 1);
    int bs[4];
    #pragma unroll
    for (int i = 0; i < 4; i++)
        if (d[i] >= 0) {
            int b = d[i] >> 7;
            bs[i] = gbase[b] + bcnt[blockIdx.x * NB + b];
        }
    #pragma unroll
    for (int i = 0; i < 4; i++)
        if (d[i] >= 0) {
            uint4 v;
            v.x = (unsigned)s[i];
            v.y = (unsigned)d[i];
            v.z = pk2(p[i].x, p[i].y);
            v.w = pk2(p[i].z, p[i].w);
            epk[bs[i] + lr[i]] = v;
        }
}

// ---------------------------------------------------------------------------
// D: fine sort within each coarse bucket + emit off[] (loads batched)
// ---------------------------------------------------------------------------
__global__ __launch_bounds__(1024) void fine_sort_kernel(
    const int* __restrict__ gbase, uint4* __restrict__ epk, int* __restrict__ off)
{
    __shared__ int hist[128];
    __shared__ int fb[128];
    int t = threadIdx.x;
    int b = blockIdx.x;
    int S = gbase[b], E = gbase[b + 1];
    if (t < 128) hist[t] = 0;
    __syncthreads();

    uint4 r[12];
    #pragma unroll
    for (int i = 0; i < 12; i++) {
        int gi = S + i * 1024 + t;
        if (gi < E) r[i] = epk[gi];
    }
    int lr[12];
    #pragma unroll
    for (int i = 0; i < 12; i++) {
        int gi = S + i * 1024 + t;
        if (gi < E) lr[i] = atomicAdd(&hist[(int)(r[i].y & 127u)], 1);
    }
    __syncthreads();
    if (t < 128) fb[t] = hist[t];
    __syncthreads();
    for (int o = 1; o < 128; o <<= 1) {
        int v = 0;
        if (t < 128 && t >= o) v = fb[t - o];
        __syncthreads();
        if (t < 128) fb[t] += v;
        __syncthreads();
    }
    int d0 = b << 7;
    if (t < 128 && d0 + t < NN) off[d0 + t] = S + fb[t] - hist[t];
    if (b == NB - 1 && t == 0) off[NN] = NE;
    __syncthreads();
    #pragma unroll
    for (int i = 0; i < 12; i++) {
        int gi = S + i * 1024 + t;
        if (gi < E) {
            int fd = (int)(r[i].y & 127u);
            int pos = S + (fb[fd] - hist[fd]) + lr[i];
            epk[pos] = r[i];
        }
    }
}

// ---------------------------------------------------------------------------
// MFMA edge kernel, half-window staging WITH RESTAGING (fixes R18 spill):
// second-half records are re-loaded after the first epilogue instead of held
// live. hbuf = [64 j][36 edge] bf16 per wave = 4.6KB -> 9.2KB/block ->
// 16 blocks/CU. Live-across-epilogue state: Bf[8] + cursors only.
// ---------------------------------------------------------------------------
__global__ __launch_bounds__(128, 5) void edge_mfma_kernel(
    const unsigned short* __restrict__ xb,
    const uint4* __restrict__ epk,
    const int* __restrict__ off,
    const unsigned short* __restrict__ w1b,
    float* __restrict__ hag)
{
    __shared__ unsigned short hbuf[2][64 * 36];
    int tid = threadIdx.x;
    int lane = tid & 63;
    int wid = tid >> 6;
    int wave = blockIdx.x * 2 + wid;
    int base = wave * 64;
    if (base >= NE) return;
    int ar = lane & 15;
    int ap = lane >> 4;
    unsigned short* hb = &hbuf[wid][0];
    int half = (ap & 1) * 8;

    bf16x8 Bf[8];
    const bf16x8* w1v = reinterpret_cast<const bf16x8*>(w1b);
    #pragma unroll
    for (int i = 0; i < 8; i++) Bf[i] = w1v[i * 64 + lane];

#define DO_TILE(EV, A0, HT) do {                                               \
    bf16x8 a1 = (bf16x8)0;                                                     \
    if (ap == 0) {                                                             \
        a1[0] = (short)(EV.z & 0xffffu);                                       \
        a1[1] = (short)(EV.z >> 16);                                           \
        a1[2] = (short)(EV.w & 0xffffu);                                       \
        a1[3] = (short)(EV.w >> 16);                                           \
        a1[4] = (short)0x3f80;                                                 \
    }                                                                          \
    f32x4 C0 = {0.f, 0.f, 0.f, 0.f}, C1 = C0, C2 = C0, C3 = C0;                \
    C0 = __builtin_amdgcn_mfma_f32_16x16x32_bf16(A0, Bf[0], C0, 0, 0, 0);      \
    C0 = __builtin_amdgcn_mfma_f32_16x16x32_bf16(a1, Bf[1], C0, 0, 0, 0);      \
    C1 = __builtin_amdgcn_mfma_f32_16x16x32_bf16(A0, Bf[2], C1, 0, 0, 0);      \
    C1 = __builtin_amdgcn_mfma_f32_16x16x32_bf16(a1, Bf[3], C1, 0, 0, 0);      \
    C2 = __builtin_amdgcn_mfma_f32_16x16x32_bf16(A0, Bf[4], C2, 0, 0, 0);      \
    C2 = __builtin_amdgcn_mfma_f32_16x16x32_bf16(a1, Bf[5], C2, 0, 0, 0);      \
    C3 = __builtin_amdgcn_mfma_f32_16x16x32_bf16(A0, Bf[6], C3, 0, 0, 0);      \
    C3 = __builtin_amdgcn_mfma_f32_16x16x32_bf16(a1, Bf[7], C3, 0, 0, 0);      \
    int eoff = (HT) * 16 + ap * 4;                                             \
    {                                                                          \
        unsigned lov = pk2(fmaxf(C0[0], 0.f), fmaxf(C0[1], 0.f));              \
        unsigned hiv = pk2(fmaxf(C0[2], 0.f), fmaxf(C0[3], 0.f));              \
        *reinterpret_cast<uint2*>(hb + (0 * 16 + ar) * 36 + eoff) = make_uint2(lov, hiv); \
    }                                                                          \
    {                                                                          \
        unsigned lov = pk2(fmaxf(C1[0], 0.f), fmaxf(C1[1], 0.f));              \
        unsigned hiv = pk2(fmaxf(C1[2], 0.f), fmaxf(C1[3], 0.f));              \
        *reinterpret_cast<uint2*>(hb + (1 * 16 + ar) * 36 + eoff) = make_uint2(lov, hiv); \
    }                                                                          \
    {                                                                          \
        unsigned lov = pk2(fmaxf(C2[0], 0.f), fmaxf(C2[1], 0.f));              \
        unsigned hiv = pk2(fmaxf(C2[2], 0.f), fmaxf(C2[3], 0.f));              \
        *reinterpret_cast<uint2*>(hb + (2 * 16 + ar) * 36 + eoff) = make_uint2(lov, hiv); \
    }                                                                          \
    {                                                                          \
        unsigned lov = pk2(fmaxf(C3[0], 0.f), fmaxf(C3[1], 0.f));              \
        unsigned hiv = pk2(fmaxf(C3[2], 0.f), fmaxf(C3[3], 0.f));              \
        *reinterpret_cast<uint2*>(hb + (3 * 16 + ar) * 36 + eoff) = make_uint2(lov, hiv); \
    }                                                                          \
} while (0)

#define EPILOGUE(HSTART, HLIM) do {                                            \
    const unsigned short* hr = hb + lane * 36;                                 \
    while (e < (HLIM)) {                                                       \
        int segend = off[d + 1];                                               \
        int eend = segend < (HLIM) ? segend : (HLIM);                          \
        float acc = 0.f;                                                       \
        int i = e - (HSTART), iend = eend - (HSTART);                          \
        for (; (i & 3) != 0 && i < iend; ++i) acc += bf2f(hr[i]);              \
        for (; i + 4 <= iend; i += 4) {                                        \
            uint2 u = *reinterpret_cast<const uint2*>(hr + i);                 \
            acc += __uint_as_float(u.x << 16) + __uint_as_float(u.x & 0xffff0000u) \
                 + __uint_as_float(u.y << 16) + __uint_as_float(u.y & 0xffff0000u); \
        }                                                                      \
        for (; i < iend; ++i) acc += bf2f(hr[i]);                              \
        unsafeAtomicAdd(&hag[(size_t)d * 64 + lane], acc);                     \
        e = eend;                                                              \
        if (segend <= (HLIM)) ++d;                                             \
    }                                                                          \
} while (0)

    int d, e;
    // ---- half 0: edges [base, base+32) ----
    {
        uint4 ev0 = epk[base + 0  + ar];
        uint4 ev1 = epk[base + 16 + ar];
        d = __builtin_amdgcn_readfirstlane((int)ev0.y);
        e = base;
        int r0 = (ap < 2) ? (int)ev0.y : (int)ev0.x;
        int r1 = (ap < 2) ? (int)ev1.y : (int)ev1.x;
        bf16x8 a00 = *reinterpret_cast<const bf16x8*>(xb + (size_t)r0 * 16 + half);
        bf16x8 a01 = *reinterpret_cast<const bf16x8*>(xb + (size_t)r1 * 16 + half);
        DO_TILE(ev0, a00, 0);
        DO_TILE(ev1, a01, 1);
    }
    asm volatile("s_waitcnt lgkmcnt(0)" ::: "memory");
    __builtin_amdgcn_sched_barrier(0);
    EPILOGUE(base, base + 32);
    asm volatile("s_waitcnt lgkmcnt(0)" ::: "memory");
    __builtin_amdgcn_sched_barrier(0);

    // ---- half 1: edges [base+32, base+64), records re-loaded (L2-hot) ----
    {
        uint4 ev2 = epk[base + 32 + ar];
        uint4 ev3 = epk[base + 48 + ar];
        int r2 = (ap < 2) ? (int)ev2.y : (int)ev2.x;
        int r3 = (ap < 2) ? (int)ev3.y : (int)ev3.x;
        bf16x8 a02 = *reinterpret_cast<const bf16x8*>(xb + (size_t)r2 * 16 + half);
        bf16x8 a03 = *reinterpret_cast<const bf16x8*>(xb + (size_t)r3 * 16 + half);
        DO_TILE(ev2, a02, 0);
        DO_TILE(ev3, a03, 1);
    }
    asm volatile("s_waitcnt lgkmcnt(0)" ::: "memory");
    __builtin_amdgcn_sched_barrier(0);
    EPILOGUE(base + 32, base + 64);
#undef DO_TILE
#undef EPILOGUE
}

// ---------------------------------------------------------------------------
// node update via MFMA (unchanged): per wave = 16 nodes.
// ---------------------------------------------------------------------------
__global__ __launch_bounds__(256) void node_mfma_kernel(
    const unsigned short* __restrict__ xb, unsigned short* __restrict__ xbn,
    float* __restrict__ hag, const int* __restrict__ off,
    const unsigned short* __restrict__ nf,
    const float* __restrict__ eb2,
    const float* __restrict__ nb1, const float* __restrict__ nb2,
    const float* __restrict__ fnw, const float* __restrict__ fnb,
    float* __restrict__ Hout, int writeH)
{
    __shared__ unsigned short aggt[4][16 * 16];
    __shared__ unsigned short ht[4][16 * 64];
    __shared__ float ot[4][16 * 16];
    int tid = threadIdx.x;
    int lane = tid & 63;
    int wid = tid >> 6;
    int wave = blockIdx.x * 4 + wid;
    int n0 = wave * 16;
    if (n0 >= NN) return;
    int nr = lane & 15;
    int ap = lane >> 4;

    bf16x8 Bf[8];
    const bf16x8* nfv = reinterpret_cast<const bf16x8*>(nf);
    #pragma unroll
    for (int i = 0; i < 8; i++) Bf[i] = nfv[i * 64 + lane];

    float* hrow = hag + (size_t)(n0 + nr) * 64 + ap * 8;
    float4* h0p = reinterpret_cast<float4*>(hrow);
    float4* h1p = reinterpret_cast<float4*>(hrow + 32);
    float4 ha = h0p[0], hc = h0p[1];
    float4 he = h1p[0], hg = h1p[1];
    float4 z = {0.f, 0.f, 0.f, 0.f};
    h0p[0] = z; h0p[1] = z; h1p[0] = z; h1p[1] = z;
    bf16x8 agA0 = mk8(pk2(ha.x, ha.y), pk2(ha.z, ha.w), pk2(hc.x, hc.y), pk2(hc.z, hc.w));
    bf16x8 agA1 = mk8(pk2(he.x, he.y), pk2(he.z, he.w), pk2(hg.x, hg.y), pk2(hg.z, hg.w));
    f32x4 Cag = {0.f, 0.f, 0.f, 0.f};
    Cag = __builtin_amdgcn_mfma_f32_16x16x32_bf16(agA0, Bf[0], Cag, 0, 0, 0);
    Cag = __builtin_amdgcn_mfma_f32_16x16x32_bf16(agA1, Bf[1], Cag, 0, 0, 0);

    int bn = n0 + ap * 4;
    int o0 = off[bn], o1 = off[bn + 1], o2 = off[bn + 2], o3 = off[bn + 3], o4 = off[bn + 4];
    float ebv = eb2[nr];
    {
        int dgs[4] = {o1 - o0, o2 - o1, o3 - o2, o4 - o3};
        #pragma unroll
        for (int r = 0; r < 4; r++) {
            float inv = 1.0f / (float)(dgs[r] > 0 ? dgs[r] : 1);
            float val = Cag[r] * inv + ((dgs[r] > 0) ? ebv : 0.f);
            aggt[wid][(ap * 4 + r) * 16 + nr] = f2bf(val);
        }
    }
    asm volatile("s_waitcnt lgkmcnt(0)" ::: "memory");
    __builtin_amdgcn_sched_barrier(0);

    bf16x8 uA;
    if (ap < 2) uA = *reinterpret_cast<const bf16x8*>(xb + (size_t)(n0 + nr) * 16 + ap * 8);
    else        uA = *reinterpret_cast<const bf16x8*>(&aggt[wid][nr * 16 + (ap - 2) * 8]);

    f32x4 Ch0 = {0.f, 0.f, 0.f, 0.f}, Ch1 = Ch0, Ch2 = Ch0, Ch3 = Ch0;
    Ch0 = __builtin_amdgcn_mfma_f32_16x16x32_bf16(uA, Bf[2], Ch0, 0, 0, 0);
    Ch1 = __builtin_amdgcn_mfma_f32_16x16x32_bf16(uA, Bf[3], Ch1, 0, 0, 0);
    Ch2 = __builtin_amdgcn_mfma_f32_16x16x32_bf16(uA, Bf[4], Ch2, 0, 0, 0);
    Ch3 = __builtin_amdgcn_mfma_f32_16x16x32_bf16(uA, Bf[5], Ch3, 0, 0, 0);

#define H_EPI(C, TT) do {                                                      \
    int j = (TT) * 16 + nr;                                                    \
    float bv = nb1[j];                                                         \
    _Pragma("unroll")                                                          \
    for (int r = 0; r < 4; r++) {                                              \
        float h = fmaxf(C[r] + bv, 0.f);                                       \
        ht[wid][(ap * 4 + r) * 64 + j] = f2bf(h);                              \
    }                                                                          \
} while (0)
    H_EPI(Ch0, 0); H_EPI(Ch1, 1); H_EPI(Ch2, 2); H_EPI(Ch3, 3);
#undef H_EPI

    asm volatile("s_waitcnt lgkmcnt(0)" ::: "memory");
    __builtin_amdgcn_sched_barrier(0);

    bf16x8 hA0 = *reinterpret_cast<const bf16x8*>(&ht[wid][nr * 64 + ap * 8]);
    bf16x8 hA1 = *reinterpret_cast<const bf16x8*>(&ht[wid][nr * 64 + 32 + ap * 8]);
    f32x4 Co = {0.f, 0.f, 0.f, 0.f};
    Co = __builtin_amdgcn_mfma_f32_16x16x32_bf16(hA0, Bf[6], Co, 0, 0, 0);
    Co = __builtin_amdgcn_mfma_f32_16x16x32_bf16(hA1, Bf[7], Co, 0, 0, 0);
    {
        float bv = nb2[nr];
        #pragma unroll
        for (int r = 0; r < 4; r++) ot[wid][(ap * 4 + r) * 16 + nr] = Co[r] + bv;
    }
    asm volatile("s_waitcnt lgkmcnt(0)" ::: "memory");
    __builtin_amdgcn_sched_barrier(0);

    if (lane < 16) {
        const float* orow = &ot[wid][lane * 16];
        float o[16];
        #pragma unroll
        for (int k = 0; k < 16; k++) o[k] = orow[k];
        unsigned pk[8];
        #pragma unroll
        for (int i = 0; i < 8; i++) pk[i] = pk2(o[2 * i], o[2 * i + 1]);
        uint4* xo = reinterpret_cast<uint4*>(xbn + (size_t)(n0 + lane) * 16);
        xo[0] = make_uint4(pk[0], pk[1], pk[2], pk[3]);
        xo[1] = make_uint4(pk[4], pk[5], pk[6], pk[7]);
        if (writeH) {
            float s = fnb[0];
            #pragma unroll
            for (int k = 0; k < 16; k++) s += o[k] * fnw[k];
            Hout[n0 + lane] = s;
        }
    }
}

extern "C" void kernel_launch(void* const* d_in, const int* in_sizes, int n_in,
                              void* d_out, int out_size, void* d_ws, size_t ws_size,
                              hipStream_t stream)
{
    const float* leak = (const float*)d_in[0];
    const float* pa   = (const float*)d_in[1];
    const int*   ei   = (const int*)d_in[2];
    const float* neww = (const float*)d_in[3];
    const float* newb = (const float*)d_in[4];
    const float* eeW  = (const float*)d_in[5];
    const float* eeB  = (const float*)d_in[6];
    const float* ew1  = (const float*)d_in[7];
    const float* eb1  = (const float*)d_in[8];
    const float* ew2  = (const float*)d_in[9];
    const float* eb2  = (const float*)d_in[10];
    const float* nw1  = (const float*)d_in[11];
    const float* nb1  = (const float*)d_in[12];
    const float* nw2  = (const float*)d_in[13];
    const float* nb2  = (const float*)d_in[14];
    const float* fnw  = (const float*)d_in[15];
    const float* fnb  = (const float*)d_in[16];
    const float* few  = (const float*)d_in[17];
    const float* feb  = (const float*)d_in[18];

    char* wsb = (char*)d_ws;
    float*          hag   = (float*)(wsb + B_HAG);
    float*          qw    = (float*)(wsb + B_QW);
    unsigned short* nf    = (unsigned short*)(wsb + B_NF);
    unsigned short* w1b   = (unsigned short*)(wsb + B_W1B);
    unsigned short* xb0   = (unsigned short*)(wsb + B_XB0);
    unsigned short* xb1   = (unsigned short*)(wsb + B_XB1);
    uint4*          epk   = (uint4*)(wsb + B_EPK);
    int*            off   = (int*)(wsb + B_OFF);
    int*            bcnt  = (int*)(wsb + B_BCNT);
    int*            gbase = (int*)(wsb + B_BASE);
    int*            gtot  = (int*)(wsb + B_GTOT);

    float* H = (float*)d_out;
    float* q = (float*)d_out + NN;
    const int* dstp = ei + NE;

    fused_init_kernel<<<CBLK, 1024, 0, stream>>>(
        ew1, eb1, nw1, ew2, nw2, eeW, eeB, few, feb, w1b, nf, qw,
        leak, neww, newb, xb0, hag, dstp, bcnt);
    scan_blocks_kernel<<<NB, 512, 0, stream>>>(bcnt, gtot);
    scan_top_kernel<<<1, 512, 0, stream>>>(gtot, gbase);
    bucket_scatter_kernel<<<CBLK, 1024, 0, stream>>>(ei, pa, bcnt, gbase, qw, q, epk);
    fine_sort_kernel<<<NB, 1024, 0, stream>>>(gbase, epk, off);

    int nwaves = NN / 16;                       // 3125
    int nblocks = (nwaves + 3) / 4;             // 782

    unsigned short* xcur = xb0;
    unsigned short* xnxt = xb1;
    for (int l = 0; l < 3; l++) {
        edge_mfma_kernel<<<NE / 128, 128, 0, stream>>>(
            xcur, epk, off, w1b + l * 4096, hag);
        node_mfma_kernel<<<nblocks, 256, 0, stream>>>(
            xcur, xnxt, hag, off, nf + l * 4096, eb2 + l * 16,
            nb1 + l * 64, nb2 + l * 16, fnw, fnb, H, (l == 2) ? 1 : 0);
        unsigned short* tmp = xcur; xcur = xnxt; xnxt = tmp;
    }
}